// Round 1
// baseline (1121.191 us; speedup 1.0000x reference)
//
#include <hip/hip_runtime.h>
#include <math.h>

#define Nn 4096
#define Ee 32768
#define Bb 64
#define FINc 128
#define Dd 64
#define SIGf 0.15f
#define LAMf 0.01f
#define EPSf 1e-5f

// ---------------- tkl (output element 64) ----------------
__global__ void k_tkl(const float* __restrict__ preW, const float* __restrict__ preb,
                      const float* __restrict__ postW, const float* __restrict__ postb,
                      const float* __restrict__ outW, const float* __restrict__ outb,
                      float* __restrict__ y) {
  int tid = threadIdx.x;
  const float logc = logf(SIGf * sqrtf(6.28318530717958647692f));
  const float c2 = 0.5f / (SIGf * SIGf);
  float acc = 0.f;
  for (int i = tid; i < FINc*Dd; i += 256) { float w = preW[i];  acc += c2*w*w + logc; }
  for (int i = tid; i < Dd; i += 256)      { float w = preb[i];  acc += c2*w*w + logc; }
  for (int i = tid; i < Dd*Dd; i += 256)   { float w = postW[i]; acc += c2*w*w + logc; }
  for (int i = tid; i < Dd; i += 256)      { float w = postb[i]; acc += c2*w*w + logc; }
  for (int i = tid; i < Dd; i += 256)      { float w = outW[i];  acc += c2*w*w + logc; }
  if (tid == 0)                            { float w = outb[0];  acc += c2*w*w + logc; }
  __shared__ float red[256];
  red[tid] = acc; __syncthreads();
  for (int s = 128; s > 0; s >>= 1) { if (tid < s) red[tid] += red[tid+s]; __syncthreads(); }
  if (tid == 0) y[Bb] = red[0];
}

// ---------------- count in-degree ----------------
__global__ void k_count(const int* __restrict__ dst, float* __restrict__ cnt) {
  int e = blockIdx.x * 256 + threadIdx.x;
  if (e < Ee) atomicAdd(&cnt[dst[e]], 1.0f);
}

// ---------------- pre FC + relu ----------------
__global__ void k_prefc(const float* __restrict__ x, const float* __restrict__ W,
                        const float* __restrict__ b, float* __restrict__ out,
                        float* __restrict__ h) {
  int n = blockIdx.x, d = threadIdx.x;
  __shared__ float xs[FINc];
  xs[d] = x[n*FINc + d];
  xs[d+64] = x[n*FINc + 64 + d];
  __syncthreads();
  float acc = b[d];
  #pragma unroll 8
  for (int k = 0; k < FINc; ++k) acc += xs[k] * W[k*Dd + d];
  acc = fmaxf(acc, 0.f);
  out[n*Dd + d] = acc;
  h[n*Dd + d] = acc;
}

// ---------------- THE BIG ONE: fused edge-MLP + per-edge matmul + scatter ----------------
// msg[e,o] = sum_{h,f} hid[e,h]*s[e,f]*W2[h,f*64+o] + sum_f s[e,f]*b2[f*64+o]
// hid[e,h] = relu(sum_k ea[e,k]*w1[k,h] + b1[h]);  s[e,:] = out[src[e],:]
#define MAC16(ACC, AV, BV) \
  ACC[0][0] += AV.x*BV.x; ACC[0][1] += AV.x*BV.y; ACC[0][2] += AV.x*BV.z; ACC[0][3] += AV.x*BV.w; \
  ACC[1][0] += AV.y*BV.x; ACC[1][1] += AV.y*BV.y; ACC[1][2] += AV.y*BV.z; ACC[1][3] += AV.y*BV.w; \
  ACC[2][0] += AV.z*BV.x; ACC[2][1] += AV.z*BV.y; ACC[2][2] += AV.z*BV.z; ACC[2][3] += AV.z*BV.w; \
  ACC[3][0] += AV.w*BV.x; ACC[3][1] += AV.w*BV.y; ACC[3][2] += AV.w*BV.z; ACC[3][3] += AV.w*BV.w;

__global__ __launch_bounds__(256) void k_msg(
    const float* __restrict__ out, const float* __restrict__ edge_attr,
    const float* __restrict__ w1, const float* __restrict__ b1,
    const float* __restrict__ w2, const float* __restrict__ b2,
    const int* __restrict__ src, const int* __restrict__ dst,
    float* __restrict__ agg) {
  __shared__ __align__(16) float sT[64*68];    // s transposed [f][e], stride 68 (16B-aligned rows)
  __shared__ __align__(16) float hidT[64*65];  // hid transposed [h][e]
  __shared__ __align__(16) float wsh[4096];    // staging: ea tile -> W2 chunks -> b2
  __shared__ int srcv[64];
  __shared__ int dstv[64];

  const int tid = threadIdx.x;
  const int ebase = blockIdx.x * 64;
  if (tid < 64) { srcv[tid] = src[ebase + tid]; dstv[tid] = dst[ebase + tid]; }

  // stage edge_attr tile (contiguous 4096 floats) into wsh, w1 (4096) into sT scratch
  {
    const float4* eaf = (const float4*)(edge_attr + ebase*64);
    const float4* w1f = (const float4*)w1;
    #pragma unroll
    for (int q = 0; q < 4; ++q) {
      ((float4*)wsh)[tid + 256*q] = eaf[tid + 256*q];
      ((float4*)sT )[tid + 256*q] = w1f[tid + 256*q];   // sT[0..4095] = w1 temporarily
    }
  }
  __syncthreads();

  // hid compute: thread owns h = tid&63, 16 edges e = (tid>>6) + 4*it
  {
    const int hh = tid & 63;
    float acc[16];
    #pragma unroll
    for (int it = 0; it < 16; ++it) acc[it] = 0.f;
    #pragma unroll 4
    for (int k = 0; k < 64; ++k) {
      float w1v = sT[k*64 + hh];
      #pragma unroll
      for (int it = 0; it < 16; ++it)
        acc[it] += wsh[((tid>>6) + 4*it)*64 + k] * w1v;
    }
    float bv = b1[hh];
    #pragma unroll
    for (int it = 0; it < 16; ++it)
      hidT[hh*65 + (tid>>6) + 4*it] = fmaxf(acc[it] + bv, 0.f);
  }
  __syncthreads();

  // stage sT[f][e] = out[srcv[e]*64 + f]  (overwrites w1 scratch)
  #pragma unroll
  for (int it = 0; it < 16; ++it) {
    int idx = tid + 256*it;
    int f = idx & 63, e = idx >> 6;
    sT[f*68 + e] = out[srcv[e]*64 + f];
  }

  const int tx4 = (tid & 15) << 2;   // output cols o
  const int ty4 = (tid >> 4) << 2;   // edge rows e
  float acc[4][4] = {{0.f}};

  for (int h = 0; h < 64; ++h) {
    __syncthreads();
    const float4* w2c = (const float4*)(w2 + h*4096);
    #pragma unroll
    for (int q = 0; q < 4; ++q) ((float4*)wsh)[tid + 256*q] = w2c[tid + 256*q];
    __syncthreads();
    float hc[4];
    #pragma unroll
    for (int i = 0; i < 4; ++i) hc[i] = hidT[h*65 + ty4 + i];
    float a2[4][4] = {{0.f}};
    #pragma unroll 4
    for (int f = 0; f < 64; ++f) {
      float4 av = *(const float4*)(sT + f*68 + ty4);
      float4 bv = *(const float4*)(wsh + f*64 + tx4);
      MAC16(a2, av, bv)
    }
    #pragma unroll
    for (int i = 0; i < 4; ++i)
      #pragma unroll
      for (int j = 0; j < 4; ++j) acc[i][j] += hc[i] * a2[i][j];
  }

  // bias term: += sum_f s[e,f]*b2[f*64+o]
  __syncthreads();
  {
    const float4* b2c = (const float4*)b2;
    #pragma unroll
    for (int q = 0; q < 4; ++q) ((float4*)wsh)[tid + 256*q] = b2c[tid + 256*q];
  }
  __syncthreads();
  #pragma unroll 4
  for (int f = 0; f < 64; ++f) {
    float4 av = *(const float4*)(sT + f*68 + ty4);
    float4 bv = *(const float4*)(wsh + f*64 + tx4);
    MAC16(acc, av, bv)
  }

  // scatter-add into agg
  #pragma unroll
  for (int i = 0; i < 4; ++i) {
    int dn = dstv[ty4 + i];
    #pragma unroll
    for (int j = 0; j < 4; ++j)
      atomicAdd(&agg[dn*64 + tx4 + j], acc[i][j]);
  }
}

// ---------------- m = agg/cnt + out@root_w + root_b ; s = softmax(m@gn_lin) ----------------
__global__ void k_m(const float* __restrict__ agg, const float* __restrict__ cnt,
                    const float* __restrict__ out, const float* __restrict__ rootw,
                    const float* __restrict__ rootb, const float* __restrict__ gnlin,
                    float* __restrict__ m, float* __restrict__ sbuf) {
  int n = blockIdx.x, d = threadIdx.x;
  __shared__ float osh[64];
  __shared__ float msh[64];
  __shared__ float lsm[16];
  osh[d] = out[n*64 + d];
  __syncthreads();
  float c = fmaxf(cnt[n], 1.f);
  float acc = agg[n*64 + d] / c + rootb[d];
  #pragma unroll 8
  for (int k = 0; k < 64; ++k) acc += osh[k] * rootw[k*64 + d];
  m[n*64 + d] = acc;
  msh[d] = acc;
  __syncthreads();
  if (d < 10) {
    float lg = 0.f;
    for (int k = 0; k < 64; ++k) lg += msh[k] * gnlin[k*10 + d];
    lsm[d] = lg;
  }
  __syncthreads();
  if (d < 10) {
    float mx = -1e30f;
    for (int g = 0; g < 10; ++g) mx = fmaxf(mx, lsm[g]);
    float sum = 0.f;
    for (int g = 0; g < 10; ++g) sum += expf(lsm[g] - mx);
    sbuf[n*16 + d] = expf(lsm[d] - mx) / sum;
  }
}

// ---------------- batch-norm statistics: sums and sumsqs of t = s[g]*m[d] ----------------
__global__ void k_stats(const float* __restrict__ m, const float* __restrict__ sbuf,
                        float* __restrict__ stats) {
  __shared__ float msh[64*64];
  __shared__ float ssh[64*16];
  int tid = threadIdx.x;
  int nb = blockIdx.x * 64;
  #pragma unroll
  for (int it = 0; it < 16; ++it) msh[tid + 256*it] = m[nb*64 + tid + 256*it];
  #pragma unroll
  for (int it = 0; it < 4; ++it) ssh[tid + 256*it] = sbuf[nb*16 + tid + 256*it];
  __syncthreads();
  for (int c = tid; c < 640; c += 256) {
    int g = c >> 6, d = c & 63;
    float a1 = 0.f, a2 = 0.f;
    #pragma unroll 8
    for (int n = 0; n < 64; ++n) {
      float t = ssh[n*16 + g] * msh[n*64 + d];
      a1 += t; a2 += t*t;
    }
    atomicAdd(&stats[c], a1);
    atomicAdd(&stats[640 + c], a2);
  }
}

// ---------------- DiffGroupNorm finalize + relu + GRU + residual ----------------
__global__ void k_normgru(const float* __restrict__ m, const float* __restrict__ sbuf,
                          const float* __restrict__ stats, const float* __restrict__ gamma,
                          const float* __restrict__ beta, const float* __restrict__ wih,
                          const float* __restrict__ whh, const float* __restrict__ bih,
                          const float* __restrict__ bhh, float* __restrict__ h,
                          float* __restrict__ out) {
  int n = blockIdx.x, d = threadIdx.x;
  __shared__ float ssh[16];
  __shared__ float msh[64];
  __shared__ float hsh[64];
  __shared__ float gish[192];
  __shared__ float ghsh[192];
  if (d < 10) ssh[d] = sbuf[n*16 + d];
  float mv = m[n*64 + d];
  float hv = h[n*64 + d];
  hsh[d] = hv;
  __syncthreads();
  const float invN = 1.f / (float)Nn;
  float accn = 0.f;
  #pragma unroll
  for (int g = 0; g < 10; ++g) {
    int c = g*64 + d;
    float mu = stats[c] * invN;
    float var = stats[640 + c] * invN - mu*mu;
    float t = ssh[g] * mv;
    accn += (t - mu) * (1.0f / sqrtf(var + EPSf)) * gamma[c] + beta[c];
  }
  float mr = fmaxf(mv + LAMf * accn, 0.f);
  msh[d] = mr;
  __syncthreads();
  #pragma unroll
  for (int p = 0; p < 3; ++p) {
    int j = p*64 + d;
    float gi = bih[j], gh = bhh[j];
    #pragma unroll 8
    for (int k = 0; k < 64; ++k) {
      gi += msh[k] * wih[j*64 + k];
      gh += hsh[k] * whh[j*64 + k];
    }
    gish[j] = gi; ghsh[j] = gh;
  }
  __syncthreads();
  float r = 1.f / (1.f + expf(-(gish[d] + ghsh[d])));
  float z = 1.f / (1.f + expf(-(gish[64 + d] + ghsh[64 + d])));
  float nn = tanhf(gish[128 + d] + r * ghsh[128 + d]);
  float hn = (1.f - z) * nn + z * hv;
  h[n*64 + d] = hn;
  out[n*64 + d] = hn + out[n*64 + d];   // out held prev; residual
}

// ---------------- global mean pool (atomic) ----------------
__global__ void k_pool(const float* __restrict__ out, const int* __restrict__ batch,
                       float* __restrict__ pooled, float* __restrict__ pcnt) {
  int idx = blockIdx.x * 256 + threadIdx.x;    // over N*64
  int n = idx >> 6, d = idx & 63;
  int b = batch[n];
  atomicAdd(&pooled[b*64 + d], out[idx]);
  if (d == 0) atomicAdd(&pcnt[b], 1.f);
}

// ---------------- post FC + output ----------------
__global__ void k_final(const float* __restrict__ pooled, const float* __restrict__ pcnt,
                        const float* __restrict__ postW, const float* __restrict__ postb,
                        const float* __restrict__ outW, const float* __restrict__ outb,
                        float* __restrict__ y) {
  int b = blockIdx.x, d = threadIdx.x;
  __shared__ float pl[64];
  float c = fmaxf(pcnt[b], 1.f);
  pl[d] = pooled[b*64 + d] / c;
  __syncthreads();
  float acc = postb[d];
  #pragma unroll 8
  for (int k = 0; k < 64; ++k) acc += pl[k] * postW[k*64 + d];
  acc = fmaxf(acc, 0.f);
  float v = acc * outW[d];
  #pragma unroll
  for (int off = 32; off > 0; off >>= 1) v += __shfl_down(v, off, 64);
  if (d == 0) y[b] = v + outb[0];
}

extern "C" void kernel_launch(void* const* d_in, const int* in_sizes, int n_in,
                              void* d_out, int out_size, void* d_ws, size_t ws_size,
                              hipStream_t stream) {
  (void)in_sizes; (void)n_in; (void)out_size; (void)ws_size;
  const float* x        = (const float*)d_in[0];
  const float* edge_attr= (const float*)d_in[1];
  const float* preW     = (const float*)d_in[2];
  const float* preb     = (const float*)d_in[3];
  const float* ew1      = (const float*)d_in[4];
  const float* eb1      = (const float*)d_in[5];
  const float* ew2      = (const float*)d_in[6];
  const float* eb2      = (const float*)d_in[7];
  const float* rootw    = (const float*)d_in[8];
  const float* rootb    = (const float*)d_in[9];
  const float* gwih     = (const float*)d_in[10];
  const float* gwhh     = (const float*)d_in[11];
  const float* gbih     = (const float*)d_in[12];
  const float* gbhh     = (const float*)d_in[13];
  const float* gnlin    = (const float*)d_in[14];
  const float* gngamma  = (const float*)d_in[15];
  const float* gnbeta   = (const float*)d_in[16];
  const float* postW    = (const float*)d_in[17];
  const float* postb    = (const float*)d_in[18];
  const float* outW     = (const float*)d_in[19];
  const float* outb     = (const float*)d_in[20];
  const int*   eidx     = (const int*)d_in[21];
  const int*   batch    = (const int*)d_in[22];
  const int* src = eidx;
  const int* dst = eidx + Ee;
  float* y = (float*)d_out;

  float* ws     = (float*)d_ws;
  float* out    = ws;                    // N*64
  float* hbuf   = out    + Nn*64;        // N*64
  float* agg    = hbuf   + Nn*64;        // N*64
  float* mbuf   = agg    + Nn*64;        // N*64
  float* sbuf   = mbuf   + Nn*64;        // N*16
  float* stats  = sbuf   + Nn*16;        // 2048 (1280 used)
  float* cnt    = stats  + 2048;         // N
  float* pooled = cnt    + Nn;           // 64*64
  float* pcnt   = pooled + 64*64;        // 64

  hipMemsetAsync(cnt, 0, Nn*sizeof(float), stream);
  hipMemsetAsync(pooled, 0, (64*64 + 64)*sizeof(float), stream);

  k_tkl<<<1, 256, 0, stream>>>(preW, preb, postW, postb, outW, outb, y);
  k_count<<<Ee/256, 256, 0, stream>>>(dst, cnt);
  k_prefc<<<Nn, 64, 0, stream>>>(x, preW, preb, out, hbuf);

  for (int i = 0; i < 3; ++i) {
    hipMemsetAsync(agg, 0, Nn*64*sizeof(float), stream);
    hipMemsetAsync(stats, 0, 1280*sizeof(float), stream);
    k_msg<<<Ee/64, 256, 0, stream>>>(out, edge_attr,
                                     ew1 + i*64*64, eb1 + i*64,
                                     ew2 + i*64*4096, eb2 + i*4096,
                                     src, dst, agg);
    k_m<<<Nn, 64, 0, stream>>>(agg, cnt, out, rootw + i*64*64, rootb + i*64,
                               gnlin + i*64*10, mbuf, sbuf);
    k_stats<<<Nn/64, 256, 0, stream>>>(mbuf, sbuf, stats);
    k_normgru<<<Nn, 64, 0, stream>>>(mbuf, sbuf, stats, gngamma + i*640, gnbeta + i*640,
                                     gwih + i*192*64, gwhh + i*192*64,
                                     gbih + i*192, gbhh + i*192, hbuf, out);
  }

  k_pool<<<Nn*64/256, 256, 0, stream>>>(out, batch, pooled, pcnt);
  k_final<<<Bb, 64, 0, stream>>>(pooled, pcnt, postW, postb, outW, outb, y);
}

// Round 2
// 489.146 us; speedup vs baseline: 2.2921x; 2.2921x over previous
//
#include <hip/hip_runtime.h>
#include <math.h>

#define Nn 4096
#define Ee 32768
#define Bb 64
#define FINc 128
#define Dd 64
#define SIGf 0.15f
#define LAMf 0.01f
#define EPSf 1e-5f

typedef __attribute__((ext_vector_type(8))) short bf16x8;
typedef __attribute__((ext_vector_type(4))) float f32x4;

__device__ inline short f2bf(float f) {
  union { float f; unsigned u; } v; v.f = f;
  unsigned r = v.u + 0x7fffu + ((v.u >> 16) & 1u);
  return (short)(r >> 16);
}
__device__ inline bf16x8 pack8v(f32x4 a, f32x4 b) {
  bf16x8 r;
  r[0]=f2bf(a.x); r[1]=f2bf(a.y); r[2]=f2bf(a.z); r[3]=f2bf(a.w);
  r[4]=f2bf(b.x); r[5]=f2bf(b.y); r[6]=f2bf(b.z); r[7]=f2bf(b.w);
  return r;
}

// ---------------- tkl (output element 64) ----------------
__global__ void k_tkl(const float* __restrict__ preW, const float* __restrict__ preb,
                      const float* __restrict__ postW, const float* __restrict__ postb,
                      const float* __restrict__ outW, const float* __restrict__ outb,
                      float* __restrict__ y) {
  int tid = threadIdx.x;
  const float logc = logf(SIGf * sqrtf(6.28318530717958647692f));
  const float c2 = 0.5f / (SIGf * SIGf);
  float acc = 0.f;
  for (int i = tid; i < FINc*Dd; i += 256) { float w = preW[i];  acc += c2*w*w + logc; }
  for (int i = tid; i < Dd; i += 256)      { float w = preb[i];  acc += c2*w*w + logc; }
  for (int i = tid; i < Dd*Dd; i += 256)   { float w = postW[i]; acc += c2*w*w + logc; }
  for (int i = tid; i < Dd; i += 256)      { float w = postb[i]; acc += c2*w*w + logc; }
  for (int i = tid; i < Dd; i += 256)      { float w = outW[i];  acc += c2*w*w + logc; }
  if (tid == 0)                            { float w = outb[0];  acc += c2*w*w + logc; }
  __shared__ float red[256];
  red[tid] = acc; __syncthreads();
  for (int s = 128; s > 0; s >>= 1) { if (tid < s) red[tid] += red[tid+s]; __syncthreads(); }
  if (tid == 0) y[Bb] = red[0];
}

// ---------------- count in-degree ----------------
__global__ void k_count(const int* __restrict__ dst, float* __restrict__ cnt) {
  int e = blockIdx.x * 256 + threadIdx.x;
  if (e < Ee) atomicAdd(&cnt[dst[e]], 1.0f);
}

// ---------------- pre FC + relu ----------------
__global__ void k_prefc(const float* __restrict__ x, const float* __restrict__ W,
                        const float* __restrict__ b, float* __restrict__ out,
                        float* __restrict__ h) {
  int n = blockIdx.x, d = threadIdx.x;
  __shared__ float xs[FINc];
  xs[d] = x[n*FINc + d];
  xs[d+64] = x[n*FINc + 64 + d];
  __syncthreads();
  float acc = b[d];
  #pragma unroll 8
  for (int k = 0; k < FINc; ++k) acc += xs[k] * W[k*Dd + d];
  acc = fmaxf(acc, 0.f);
  out[n*Dd + d] = acc;
  h[n*Dd + d] = acc;
}

// ---------------- weight prep: bf16 transposes ----------------
// w1T[l][h][f] = w1[l][f][h];  b2T[l][o][f] = b2[l][f*64+o];  w2T[l][h][o][f] = w2[l][h][f*64+o]
__global__ void k_prep(const float* __restrict__ w1, const float* __restrict__ w2,
                       const float* __restrict__ b2, short* __restrict__ w1T,
                       short* __restrict__ b2T, short* __restrict__ w2T) {
  int idx = blockIdx.x * 256 + threadIdx.x;
  if (idx < 3*64*64*64) {
    int f = idx & 63, o = (idx >> 6) & 63, h = (idx >> 12) & 63, l = idx >> 18;
    w2T[idx] = f2bf(w2[(((l*64 + h)*64 + f) << 6) + o]);
  }
  if (idx < 3*64*64) {
    int f = idx & 63, h = (idx >> 6) & 63, l = idx >> 12;
    w1T[idx] = f2bf(w1[l*4096 + f*64 + h]);
    b2T[idx] = f2bf(b2[l*4096 + f*64 + h]);  // h plays role of o here
  }
}

// ---------------- fused edge-MLP + bilinear message GEMM (MFMA) + scatter ----------------
__global__ __launch_bounds__(256) void k_msg(
    const float* __restrict__ out, const float* __restrict__ edge_attr,
    const short* __restrict__ w1T, const float* __restrict__ b1,
    const short* __restrict__ w2T, const short* __restrict__ b2T,
    const int* __restrict__ src, const int* __restrict__ dst,
    float* __restrict__ agg) {
  __shared__ __align__(16) float hidT[64*68];   // [h][e], stride 68 dwords
  __shared__ int srcv[64];
  __shared__ int dstv[64];

  const int tid  = threadIdx.x;
  const int lane = tid & 63;
  const int wave = tid >> 6;       // col group: o = wave*16 + m15
  const int m15  = lane & 15;
  const int kq   = lane >> 4;      // 0..3
  const int ebase = blockIdx.x * 64;

  if (tid < 64) { srcv[tid] = src[ebase + tid]; dstv[tid] = dst[ebase + tid]; }
  __syncthreads();

  const f32x4 zero4 = {0.f, 0.f, 0.f, 0.f};

  // ---- gather s = out[src] into A-fragments (kept in regs for the whole K-loop) ----
  bf16x8 sfrag[4][2];
  #pragma unroll
  for (int t = 0; t < 4; ++t) {
    int node = srcv[t*16 + m15];
    const float* sp = out + node*64 + kq*8;
    #pragma unroll
    for (int ks = 0; ks < 2; ++ks) {
      f32x4 a = *(const f32x4*)(sp + ks*32);
      f32x4 b = *(const f32x4*)(sp + ks*32 + 4);
      sfrag[t][ks] = pack8v(a, b);
    }
  }

  // ---- hid = relu(ea @ w1 + b1) via MFMA; write hidT[h][e] ----
  {
    const short* wp = w1T + (wave*16 + m15)*64 + kq*8;
    bf16x8 bw0 = *(const bf16x8*)(wp);
    bf16x8 bw1 = *(const bf16x8*)(wp + 32);
    float b1v = b1[wave*16 + m15];
    #pragma unroll
    for (int t = 0; t < 4; ++t) {
      const float* ep = edge_attr + (size_t)(ebase + t*16 + m15)*64 + kq*8;
      bf16x8 a0 = pack8v(*(const f32x4*)(ep),      *(const f32x4*)(ep + 4));
      bf16x8 a1 = pack8v(*(const f32x4*)(ep + 32), *(const f32x4*)(ep + 36));
      f32x4 p = __builtin_amdgcn_mfma_f32_16x16x32_bf16(a0, bw0, zero4, 0, 0, 0);
      p = __builtin_amdgcn_mfma_f32_16x16x32_bf16(a1, bw1, p, 0, 0, 0);
      f32x4 v;
      v.x = fmaxf(p.x + b1v, 0.f); v.y = fmaxf(p.y + b1v, 0.f);
      v.z = fmaxf(p.z + b1v, 0.f); v.w = fmaxf(p.w + b1v, 0.f);
      // C-frag: h = wave*16+m15 (col), e rows = t*16 + kq*4 + reg
      *(f32x4*)(hidT + (wave*16 + m15)*68 + t*16 + kq*4) = v;
    }
  }
  __syncthreads();

  // ---- K-loop over 64 h-chunks: acc[e,o] += hid[e,h] * (s @ W2_h)[e,o] ----
  f32x4 acc[4] = {zero4, zero4, zero4, zero4};
  const short* w2base = w2T + (wave*16 + m15)*64 + kq*8;   // + h*4096
  const short* b2base = b2T + (wave*16 + m15)*64 + kq*8;
  bf16x8 bc0 = *(const bf16x8*)(w2base);
  bf16x8 bc1 = *(const bf16x8*)(w2base + 32);
  for (int h = 0; h < 64; ++h) {
    const short* nb = (h < 63) ? (w2base + (h + 1)*4096) : b2base;
    bf16x8 pb0 = *(const bf16x8*)(nb);
    bf16x8 pb1 = *(const bf16x8*)(nb + 32);
    #pragma unroll
    for (int t = 0; t < 4; ++t) {
      f32x4 p = __builtin_amdgcn_mfma_f32_16x16x32_bf16(sfrag[t][0], bc0, zero4, 0, 0, 0);
      p = __builtin_amdgcn_mfma_f32_16x16x32_bf16(sfrag[t][1], bc1, p, 0, 0, 0);
      f32x4 hv = *(const f32x4*)(hidT + h*68 + t*16 + kq*4);
      acc[t].x += hv.x * p.x; acc[t].y += hv.y * p.y;
      acc[t].z += hv.z * p.z; acc[t].w += hv.w * p.w;
    }
    bc0 = pb0; bc1 = pb1;
  }
  // b2 term (scale 1)
  #pragma unroll
  for (int t = 0; t < 4; ++t) {
    f32x4 p = __builtin_amdgcn_mfma_f32_16x16x32_bf16(sfrag[t][0], bc0, zero4, 0, 0, 0);
    p = __builtin_amdgcn_mfma_f32_16x16x32_bf16(sfrag[t][1], bc1, p, 0, 0, 0);
    acc[t].x += p.x; acc[t].y += p.y; acc[t].z += p.z; acc[t].w += p.w;
  }

  // ---- scatter-add into agg ----
  const int o = wave*16 + m15;
  #pragma unroll
  for (int t = 0; t < 4; ++t) {
    #pragma unroll
    for (int r = 0; r < 4; ++r) {
      int e = t*16 + kq*4 + r;
      atomicAdd(&agg[dstv[e]*64 + o], acc[t][r]);
    }
  }
}

// ---------------- m = agg/cnt + out@root_w + root_b ; s = softmax(m@gn_lin) ----------------
__global__ void k_m(const float* __restrict__ agg, const float* __restrict__ cnt,
                    const float* __restrict__ out, const float* __restrict__ rootw,
                    const float* __restrict__ rootb, const float* __restrict__ gnlin,
                    float* __restrict__ m, float* __restrict__ sbuf) {
  int n = blockIdx.x, d = threadIdx.x;
  __shared__ float osh[64];
  __shared__ float msh[64];
  __shared__ float lsm[16];
  osh[d] = out[n*64 + d];
  __syncthreads();
  float c = fmaxf(cnt[n], 1.f);
  float acc = agg[n*64 + d] / c + rootb[d];
  #pragma unroll 8
  for (int k = 0; k < 64; ++k) acc += osh[k] * rootw[k*64 + d];
  m[n*64 + d] = acc;
  msh[d] = acc;
  __syncthreads();
  if (d < 10) {
    float lg = 0.f;
    for (int k = 0; k < 64; ++k) lg += msh[k] * gnlin[k*10 + d];
    lsm[d] = lg;
  }
  __syncthreads();
  if (d < 10) {
    float mx = -1e30f;
    for (int g = 0; g < 10; ++g) mx = fmaxf(mx, lsm[g]);
    float sum = 0.f;
    for (int g = 0; g < 10; ++g) sum += expf(lsm[g] - mx);
    sbuf[n*16 + d] = expf(lsm[d] - mx) / sum;
  }
}

// ---------------- batch-norm statistics ----------------
__global__ void k_stats(const float* __restrict__ m, const float* __restrict__ sbuf,
                        float* __restrict__ stats) {
  __shared__ float msh[64*64];
  __shared__ float ssh[64*16];
  int tid = threadIdx.x;
  int nb = blockIdx.x * 64;
  #pragma unroll
  for (int it = 0; it < 16; ++it) msh[tid + 256*it] = m[nb*64 + tid + 256*it];
  #pragma unroll
  for (int it = 0; it < 4; ++it) ssh[tid + 256*it] = sbuf[nb*16 + tid + 256*it];
  __syncthreads();
  for (int c = tid; c < 640; c += 256) {
    int g = c >> 6, d = c & 63;
    float a1 = 0.f, a2 = 0.f;
    #pragma unroll 8
    for (int n = 0; n < 64; ++n) {
      float t = ssh[n*16 + g] * msh[n*64 + d];
      a1 += t; a2 += t*t;
    }
    atomicAdd(&stats[c], a1);
    atomicAdd(&stats[640 + c], a2);
  }
}

// ---------------- DiffGroupNorm finalize + relu + GRU + residual ----------------
__global__ void k_normgru(const float* __restrict__ m, const float* __restrict__ sbuf,
                          const float* __restrict__ stats, const float* __restrict__ gamma,
                          const float* __restrict__ beta, const float* __restrict__ wih,
                          const float* __restrict__ whh, const float* __restrict__ bih,
                          const float* __restrict__ bhh, float* __restrict__ h,
                          float* __restrict__ out) {
  int n = blockIdx.x, d = threadIdx.x;
  __shared__ float ssh[16];
  __shared__ float msh[64];
  __shared__ float hsh[64];
  __shared__ float gish[192];
  __shared__ float ghsh[192];
  if (d < 10) ssh[d] = sbuf[n*16 + d];
  float mv = m[n*64 + d];
  float hv = h[n*64 + d];
  hsh[d] = hv;
  __syncthreads();
  const float invN = 1.f / (float)Nn;
  float accn = 0.f;
  #pragma unroll
  for (int g = 0; g < 10; ++g) {
    int c = g*64 + d;
    float mu = stats[c] * invN;
    float var = stats[640 + c] * invN - mu*mu;
    float t = ssh[g] * mv;
    accn += (t - mu) * (1.0f / sqrtf(var + EPSf)) * gamma[c] + beta[c];
  }
  float mr = fmaxf(mv + LAMf * accn, 0.f);
  msh[d] = mr;
  __syncthreads();
  #pragma unroll
  for (int p = 0; p < 3; ++p) {
    int j = p*64 + d;
    float gi = bih[j], gh = bhh[j];
    #pragma unroll 8
    for (int k = 0; k < 64; ++k) {
      gi += msh[k] * wih[j*64 + k];
      gh += hsh[k] * whh[j*64 + k];
    }
    gish[j] = gi; ghsh[j] = gh;
  }
  __syncthreads();
  float r = 1.f / (1.f + expf(-(gish[d] + ghsh[d])));
  float z = 1.f / (1.f + expf(-(gish[64 + d] + ghsh[64 + d])));
  float nn = tanhf(gish[128 + d] + r * ghsh[128 + d]);
  float hn = (1.f - z) * nn + z * hv;
  h[n*64 + d] = hn;
  out[n*64 + d] = hn + out[n*64 + d];
}

// ---------------- global mean pool (atomic) ----------------
__global__ void k_pool(const float* __restrict__ out, const int* __restrict__ batch,
                       float* __restrict__ pooled, float* __restrict__ pcnt) {
  int idx = blockIdx.x * 256 + threadIdx.x;
  int n = idx >> 6, d = idx & 63;
  int b = batch[n];
  atomicAdd(&pooled[b*64 + d], out[idx]);
  if (d == 0) atomicAdd(&pcnt[b], 1.f);
}

// ---------------- post FC + output ----------------
__global__ void k_final(const float* __restrict__ pooled, const float* __restrict__ pcnt,
                        const float* __restrict__ postW, const float* __restrict__ postb,
                        const float* __restrict__ outW, const float* __restrict__ outb,
                        float* __restrict__ y) {
  int b = blockIdx.x, d = threadIdx.x;
  __shared__ float pl[64];
  float c = fmaxf(pcnt[b], 1.f);
  pl[d] = pooled[b*64 + d] / c;
  __syncthreads();
  float acc = postb[d];
  #pragma unroll 8
  for (int k = 0; k < 64; ++k) acc += pl[k] * postW[k*64 + d];
  acc = fmaxf(acc, 0.f);
  float v = acc * outW[d];
  #pragma unroll
  for (int off = 32; off > 0; off >>= 1) v += __shfl_down(v, off, 64);
  if (d == 0) y[b] = v + outb[0];
}

extern "C" void kernel_launch(void* const* d_in, const int* in_sizes, int n_in,
                              void* d_out, int out_size, void* d_ws, size_t ws_size,
                              hipStream_t stream) {
  (void)in_sizes; (void)n_in; (void)out_size; (void)ws_size;
  const float* x        = (const float*)d_in[0];
  const float* edge_attr= (const float*)d_in[1];
  const float* preW     = (const float*)d_in[2];
  const float* preb     = (const float*)d_in[3];
  const float* ew1      = (const float*)d_in[4];
  const float* eb1      = (const float*)d_in[5];
  const float* ew2      = (const float*)d_in[6];
  const float* eb2      = (const float*)d_in[7];
  const float* rootw    = (const float*)d_in[8];
  const float* rootb    = (const float*)d_in[9];
  const float* gwih     = (const float*)d_in[10];
  const float* gwhh     = (const float*)d_in[11];
  const float* gbih     = (const float*)d_in[12];
  const float* gbhh     = (const float*)d_in[13];
  const float* gnlin    = (const float*)d_in[14];
  const float* gngamma  = (const float*)d_in[15];
  const float* gnbeta   = (const float*)d_in[16];
  const float* postW    = (const float*)d_in[17];
  const float* postb    = (const float*)d_in[18];
  const float* outW     = (const float*)d_in[19];
  const float* outb     = (const float*)d_in[20];
  const int*   eidx     = (const int*)d_in[21];
  const int*   batch    = (const int*)d_in[22];
  const int* src = eidx;
  const int* dst = eidx + Ee;
  float* y = (float*)d_out;

  float* ws     = (float*)d_ws;
  float* out    = ws;                     // 262144
  float* hbuf   = out    + Nn*64;         // 262144
  float* mbuf   = hbuf   + Nn*64;         // 262144
  float* sbuf   = mbuf   + Nn*64;         // 65536
  float* agg    = sbuf   + Nn*16;         // 262144
  float* stats  = agg    + Nn*64;         // 2048 (contiguous with agg for 1 memset)
  float* cnt    = stats  + 2048;          // 4096
  float* pooled = cnt    + Nn;            // 4096
  float* pcnt   = pooled + Nn;            // 64  (cnt..pcnt one memset)
  float* bfbase = pcnt   + 64;
  // align to 16B (offset is already multiple of 4 floats)
  short* w1T = (short*)bfbase;            // 3*4096
  short* b2T = w1T + 3*4096;              // 3*4096
  short* w2T = b2T + 3*4096;              // 3*262144

  hipMemsetAsync(cnt, 0, (Nn + Nn + 64)*sizeof(float), stream);

  k_prep<<<3072, 256, 0, stream>>>(ew1, ew2, eb2, w1T, b2T, w2T);
  k_tkl<<<1, 256, 0, stream>>>(preW, preb, postW, postb, outW, outb, y);
  k_count<<<Ee/256, 256, 0, stream>>>(dst, cnt);
  k_prefc<<<Nn, 64, 0, stream>>>(x, preW, preb, out, hbuf);

  for (int i = 0; i < 3; ++i) {
    hipMemsetAsync(agg, 0, (Nn*64 + 2048)*sizeof(float), stream);
    k_msg<<<Ee/64, 256, 0, stream>>>(out, edge_attr,
                                     w1T + i*4096, eb1 + i*64,
                                     w2T + i*262144, b2T + i*4096,
                                     src, dst, agg);
    k_m<<<Nn, 64, 0, stream>>>(agg, cnt, out, rootw + i*64*64, rootb + i*64,
                               gnlin + i*64*10, mbuf, sbuf);
    k_stats<<<Nn/64, 256, 0, stream>>>(mbuf, sbuf, stats);
    k_normgru<<<Nn, 64, 0, stream>>>(mbuf, sbuf, stats, gngamma + i*640, gnbeta + i*640,
                                     gwih + i*192*64, gwhh + i*192*64,
                                     gbih + i*192, gbhh + i*192, hbuf, out);
  }

  k_pool<<<Nn*64/256, 256, 0, stream>>>(out, batch, pooled, pcnt);
  k_final<<<Bb, 64, 0, stream>>>(pooled, pcnt, postW, postb, outW, outb, y);
}

// Round 3
// 379.114 us; speedup vs baseline: 2.9574x; 1.2902x over previous
//
#include <hip/hip_runtime.h>
#include <math.h>

#define Nn 4096
#define Ee 32768
#define Bb 64
#define FINc 128
#define Dd 64
#define SIGf 0.15f
#define LAMf 0.01f
#define EPSf 1e-5f

typedef __attribute__((ext_vector_type(8))) short bf16x8;
typedef __attribute__((ext_vector_type(4))) float f32x4;

__device__ inline short f2bf(float f) {
  union { float f; unsigned u; } v; v.f = f;
  unsigned r = v.u + 0x7fffu + ((v.u >> 16) & 1u);
  return (short)(r >> 16);
}
__device__ inline bf16x8 pack8v(f32x4 a, f32x4 b) {
  bf16x8 r;
  r[0]=f2bf(a.x); r[1]=f2bf(a.y); r[2]=f2bf(a.z); r[3]=f2bf(a.w);
  r[4]=f2bf(b.x); r[5]=f2bf(b.y); r[6]=f2bf(b.z); r[7]=f2bf(b.w);
  return r;
}
__device__ inline float sigm(float x) { return 1.f / (1.f + expf(-x)); }

// ---------------- tkl (output element 64) ----------------
__global__ void k_tkl(const float* __restrict__ preW, const float* __restrict__ preb,
                      const float* __restrict__ postW, const float* __restrict__ postb,
                      const float* __restrict__ outW, const float* __restrict__ outb,
                      float* __restrict__ y) {
  int tid = threadIdx.x;
  const float logc = logf(SIGf * sqrtf(6.28318530717958647692f));
  const float c2 = 0.5f / (SIGf * SIGf);
  float acc = 0.f;
  for (int i = tid; i < FINc*Dd; i += 256) { float w = preW[i];  acc += c2*w*w + logc; }
  for (int i = tid; i < Dd; i += 256)      { float w = preb[i];  acc += c2*w*w + logc; }
  for (int i = tid; i < Dd*Dd; i += 256)   { float w = postW[i]; acc += c2*w*w + logc; }
  for (int i = tid; i < Dd; i += 256)      { float w = postb[i]; acc += c2*w*w + logc; }
  for (int i = tid; i < Dd; i += 256)      { float w = outW[i];  acc += c2*w*w + logc; }
  if (tid == 0)                            { float w = outb[0];  acc += c2*w*w + logc; }
  __shared__ float red[256];
  red[tid] = acc; __syncthreads();
  for (int s = 128; s > 0; s >>= 1) { if (tid < s) red[tid] += red[tid+s]; __syncthreads(); }
  if (tid == 0) y[Bb] = red[0];
}

// ---------------- count in-degree ----------------
__global__ void k_count(const int* __restrict__ dst, float* __restrict__ cnt) {
  int e = blockIdx.x * 256 + threadIdx.x;
  if (e < Ee) atomicAdd(&cnt[dst[e]], 1.0f);
}

// ---------------- weight prep: bf16 packs/transposes ----------------
__global__ void k_prep(const float* __restrict__ w1, const float* __restrict__ w2,
                       const float* __restrict__ b2, const float* __restrict__ rootw,
                       const float* __restrict__ gwih, const float* __restrict__ gwhh,
                       const float* __restrict__ preW,
                       short* __restrict__ w1T, short* __restrict__ b2T,
                       short* __restrict__ w2T, short* __restrict__ rootwT,
                       short* __restrict__ gwihB, short* __restrict__ gwhhB,
                       short* __restrict__ preWT) {
  int idx = blockIdx.x * 256 + threadIdx.x;
  if (idx < 3*64*64*64) {
    int f = idx & 63, o = (idx >> 6) & 63, h = (idx >> 12) & 63, l = idx >> 18;
    w2T[idx] = f2bf(w2[(((l*64 + h)*64 + f) << 6) + o]);
  }
  if (idx < 3*64*64) {
    int f = idx & 63, h = (idx >> 6) & 63, l = idx >> 12;
    w1T[idx] = f2bf(w1[l*4096 + f*64 + h]);
    b2T[idx] = f2bf(b2[l*4096 + f*64 + h]);
    rootwT[idx] = f2bf(rootw[l*4096 + f*64 + h]);  // rootwT[l][d][k] = rootw[l][k][d]
  }
  if (idx < 3*192*64) {
    gwihB[idx] = f2bf(gwih[idx]);
    gwhhB[idx] = f2bf(gwhh[idx]);
  }
  if (idx < 64*128) {
    int k = idx & 127, d = idx >> 7;
    preWT[idx] = f2bf(preW[k*64 + d]);             // preWT[d][k]
  }
}

// ---------------- pre FC + relu via MFMA: out = relu(x @ preW + preb) ----------------
__global__ __launch_bounds__(256) void k_pre(const float* __restrict__ x,
                                             const short* __restrict__ preWT,
                                             const float* __restrict__ preb,
                                             float* __restrict__ out, float* __restrict__ h) {
  const int tid = threadIdx.x, lane = tid & 63, wave = tid >> 6;
  const int m15 = lane & 15, kq = lane >> 4;
  const int nb = blockIdx.x * 32;
  const f32x4 zero4 = {0.f,0.f,0.f,0.f};
  const int d = wave*16 + m15;
  bf16x8 bfr[4];
  #pragma unroll
  for (int c = 0; c < 4; ++c)
    bfr[c] = *(const bf16x8*)(preWT + d*128 + c*32 + kq*8);
  #pragma unroll
  for (int t = 0; t < 2; ++t) {
    const float* xp = x + (size_t)(nb + t*16 + m15)*128 + kq*8;
    f32x4 p = zero4;
    #pragma unroll
    for (int c = 0; c < 4; ++c) {
      bf16x8 a = pack8v(*(const f32x4*)(xp + c*32), *(const f32x4*)(xp + c*32 + 4));
      p = __builtin_amdgcn_mfma_f32_16x16x32_bf16(a, bfr[c], p, 0, 0, 0);
    }
    float bv = preb[d];
    #pragma unroll
    for (int r = 0; r < 4; ++r) {
      int node = nb + t*16 + kq*4 + r;
      float v = fmaxf(p[r] + bv, 0.f);
      out[node*64 + d] = v;
      h[node*64 + d] = v;
    }
  }
}

// ---------------- fused edge-MLP + bilinear message GEMM (MFMA) + scatter ----------------
__global__ __launch_bounds__(256) void k_msg(
    const float* __restrict__ out, const float* __restrict__ edge_attr,
    const short* __restrict__ w1T, const float* __restrict__ b1,
    const short* __restrict__ w2T, const short* __restrict__ b2T,
    const int* __restrict__ src, const int* __restrict__ dst,
    float* __restrict__ agg) {
  __shared__ __align__(16) float hidT[64*68];
  __shared__ int srcv[64];
  __shared__ int dstv[64];

  const int tid  = threadIdx.x;
  const int lane = tid & 63;
  const int wave = tid >> 6;
  const int m15  = lane & 15;
  const int kq   = lane >> 4;
  const int ebase = blockIdx.x * 64;

  if (tid < 64) { srcv[tid] = src[ebase + tid]; dstv[tid] = dst[ebase + tid]; }
  __syncthreads();

  const f32x4 zero4 = {0.f, 0.f, 0.f, 0.f};

  bf16x8 sfrag[4][2];
  #pragma unroll
  for (int t = 0; t < 4; ++t) {
    int node = srcv[t*16 + m15];
    const float* sp = out + node*64 + kq*8;
    #pragma unroll
    for (int ks = 0; ks < 2; ++ks) {
      f32x4 a = *(const f32x4*)(sp + ks*32);
      f32x4 b = *(const f32x4*)(sp + ks*32 + 4);
      sfrag[t][ks] = pack8v(a, b);
    }
  }

  {
    const short* wp = w1T + (wave*16 + m15)*64 + kq*8;
    bf16x8 bw0 = *(const bf16x8*)(wp);
    bf16x8 bw1 = *(const bf16x8*)(wp + 32);
    float b1v = b1[wave*16 + m15];
    #pragma unroll
    for (int t = 0; t < 4; ++t) {
      const float* ep = edge_attr + (size_t)(ebase + t*16 + m15)*64 + kq*8;
      bf16x8 a0 = pack8v(*(const f32x4*)(ep),      *(const f32x4*)(ep + 4));
      bf16x8 a1 = pack8v(*(const f32x4*)(ep + 32), *(const f32x4*)(ep + 36));
      f32x4 p = __builtin_amdgcn_mfma_f32_16x16x32_bf16(a0, bw0, zero4, 0, 0, 0);
      p = __builtin_amdgcn_mfma_f32_16x16x32_bf16(a1, bw1, p, 0, 0, 0);
      f32x4 v;
      v.x = fmaxf(p.x + b1v, 0.f); v.y = fmaxf(p.y + b1v, 0.f);
      v.z = fmaxf(p.z + b1v, 0.f); v.w = fmaxf(p.w + b1v, 0.f);
      *(f32x4*)(hidT + (wave*16 + m15)*68 + t*16 + kq*4) = v;
    }
  }
  __syncthreads();

  f32x4 acc[4] = {zero4, zero4, zero4, zero4};
  const short* w2base = w2T + (wave*16 + m15)*64 + kq*8;
  const short* b2base = b2T + (wave*16 + m15)*64 + kq*8;
  bf16x8 bc0 = *(const bf16x8*)(w2base);
  bf16x8 bc1 = *(const bf16x8*)(w2base + 32);
  for (int h = 0; h < 64; ++h) {
    const short* nb = (h < 63) ? (w2base + (h + 1)*4096) : b2base;
    bf16x8 pb0 = *(const bf16x8*)(nb);
    bf16x8 pb1 = *(const bf16x8*)(nb + 32);
    #pragma unroll
    for (int t = 0; t < 4; ++t) {
      f32x4 p = __builtin_amdgcn_mfma_f32_16x16x32_bf16(sfrag[t][0], bc0, zero4, 0, 0, 0);
      p = __builtin_amdgcn_mfma_f32_16x16x32_bf16(sfrag[t][1], bc1, p, 0, 0, 0);
      f32x4 hv = *(const f32x4*)(hidT + h*68 + t*16 + kq*4);
      acc[t].x += hv.x * p.x; acc[t].y += hv.y * p.y;
      acc[t].z += hv.z * p.z; acc[t].w += hv.w * p.w;
    }
    bc0 = pb0; bc1 = pb1;
  }
  #pragma unroll
  for (int t = 0; t < 4; ++t) {
    f32x4 p = __builtin_amdgcn_mfma_f32_16x16x32_bf16(sfrag[t][0], bc0, zero4, 0, 0, 0);
    p = __builtin_amdgcn_mfma_f32_16x16x32_bf16(sfrag[t][1], bc1, p, 0, 0, 0);
    acc[t].x += p.x; acc[t].y += p.y; acc[t].z += p.z; acc[t].w += p.w;
  }

  const int o = wave*16 + m15;
  #pragma unroll
  for (int t = 0; t < 4; ++t) {
    #pragma unroll
    for (int r = 0; r < 4; ++r) {
      int e = t*16 + kq*4 + r;
      atomicAdd(&agg[dstv[e]*64 + o], acc[t][r]);
    }
  }
}

// ---------------- fused: m = agg/cnt + out@rootw + rootb ; softmax ; BN stats ----------------
__global__ __launch_bounds__(256) void k_m_fused(
    const float* __restrict__ agg, const float* __restrict__ cnt,
    const float* __restrict__ out, const short* __restrict__ rootwT,
    const float* __restrict__ rootb, const float* __restrict__ gnlin,
    float* __restrict__ m, float* __restrict__ sbuf, float* __restrict__ stats) {
  __shared__ float msh[64*65];
  __shared__ float lgsh[64*12];
  __shared__ float ssh[64*16];
  const int tid = threadIdx.x, lane = tid & 63, wave = tid >> 6;
  const int m15 = lane & 15, kq = lane >> 4;
  const int nb = blockIdx.x * 64;
  const f32x4 zero4 = {0.f,0.f,0.f,0.f};
  const int d = wave*16 + m15;

  bf16x8 b0 = *(const bf16x8*)(rootwT + d*64 + kq*8);
  bf16x8 b1 = *(const bf16x8*)(rootwT + d*64 + 32 + kq*8);
  float rbv = rootb[d];
  #pragma unroll
  for (int t = 0; t < 4; ++t) {
    const float* sp = out + (size_t)(nb + t*16 + m15)*64 + kq*8;
    bf16x8 a0 = pack8v(*(const f32x4*)(sp),      *(const f32x4*)(sp + 4));
    bf16x8 a1 = pack8v(*(const f32x4*)(sp + 32), *(const f32x4*)(sp + 36));
    f32x4 p = __builtin_amdgcn_mfma_f32_16x16x32_bf16(a0, b0, zero4, 0, 0, 0);
    p = __builtin_amdgcn_mfma_f32_16x16x32_bf16(a1, b1, p, 0, 0, 0);
    #pragma unroll
    for (int r = 0; r < 4; ++r) {
      int ln = t*16 + kq*4 + r;
      int node = nb + ln;
      float mv = agg[node*64 + d] / fmaxf(cnt[node], 1.f) + rbv + p[r];
      m[node*64 + d] = mv;
      msh[ln*65 + d] = mv;
    }
  }
  __syncthreads();

  // logits
  for (int c = tid; c < 1024; c += 256) {
    int n = c >> 4, g = c & 15;
    if (g < 10) {
      float lg = 0.f;
      #pragma unroll 8
      for (int k = 0; k < 64; ++k) lg += msh[n*65 + k] * gnlin[k*10 + g];
      lgsh[n*12 + g] = lg;
    }
  }
  __syncthreads();
  // softmax
  for (int c = tid; c < 1024; c += 256) {
    int n = c >> 4, g = c & 15;
    if (g < 10) {
      float mx = -1e30f;
      #pragma unroll
      for (int gg = 0; gg < 10; ++gg) mx = fmaxf(mx, lgsh[n*12 + gg]);
      float sum = 0.f;
      #pragma unroll
      for (int gg = 0; gg < 10; ++gg) sum += expf(lgsh[n*12 + gg] - mx);
      float sv = expf(lgsh[n*12 + g] - mx) / sum;
      sbuf[(nb + n)*16 + g] = sv;
      ssh[n*16 + g] = sv;
    }
  }
  __syncthreads();
  // BN stat partials
  for (int c = tid; c < 640; c += 256) {
    int g = c >> 6, dd = c & 63;
    float a1 = 0.f, a2 = 0.f;
    #pragma unroll 8
    for (int n = 0; n < 64; ++n) {
      float t = ssh[n*16 + g] * msh[n*65 + dd];
      a1 += t; a2 += t*t;
    }
    atomicAdd(&stats[c], a1);
    atomicAdd(&stats[640 + c], a2);
  }
}

// ---------------- fused DGN-finalize + relu + GRU (MFMA) + residual ----------------
__global__ __launch_bounds__(256) void k_gru(
    const float* __restrict__ m, const float* __restrict__ sbuf,
    const float* __restrict__ stats, const float* __restrict__ gamma,
    const float* __restrict__ beta, const short* __restrict__ gwihB,
    const short* __restrict__ gwhhB, const float* __restrict__ bih,
    const float* __restrict__ bhh, float* __restrict__ h,
    float* __restrict__ out) {
  __shared__ __align__(16) float mrsh[32*68];
  __shared__ float igsh[640];
  __shared__ float Bsh[64];
  __shared__ float ssh[512];
  const int tid = threadIdx.x, lane = tid & 63, wave = tid >> 6;
  const int m15 = lane & 15, kq = lane >> 4;
  const int nb = blockIdx.x * 32;
  const f32x4 zero4 = {0.f,0.f,0.f,0.f};
  const float invN = 1.f / (float)Nn;

  if (tid < 64) {
    float bacc = 0.f;
    #pragma unroll
    for (int g = 0; g < 10; ++g) {
      int c = g*64 + tid;
      float mu = stats[c] * invN;
      float var = stats[640 + c] * invN - mu*mu;
      float ig = (1.0f / sqrtf(var + EPSf)) * gamma[c];
      igsh[c] = ig;
      bacc += beta[c] - mu * ig;
    }
    Bsh[tid] = bacc;
  }
  if (tid < 512) ssh[tid] = sbuf[nb*16 + tid];
  __syncthreads();

  for (int idx = tid; idx < 2048; idx += 256) {
    int n = idx >> 6, dd = idx & 63;
    float mv = m[(nb + n)*64 + dd];
    float SA = 0.f;
    #pragma unroll
    for (int g = 0; g < 10; ++g) SA += ssh[n*16 + g] * igsh[g*64 + dd];
    mrsh[n*68 + dd] = fmaxf(mv * (1.f + LAMf*SA) + LAMf*Bsh[dd], 0.f);
  }
  __syncthreads();

  // fragments
  bf16x8 mrf[2][2], hf[2][2];
  #pragma unroll
  for (int t = 0; t < 2; ++t) {
    const float* mp = mrsh + (t*16 + m15)*68 + kq*8;
    const float* hp = h + (size_t)(nb + t*16 + m15)*64 + kq*8;
    #pragma unroll
    for (int ks = 0; ks < 2; ++ks) {
      mrf[t][ks] = pack8v(*(const f32x4*)(mp + ks*32), *(const f32x4*)(mp + ks*32 + 4));
      hf[t][ks]  = pack8v(*(const f32x4*)(hp + ks*32), *(const f32x4*)(hp + ks*32 + 4));
    }
  }
  const int d = wave*16 + m15;
  f32x4 gi[2][3], gh[2][3];
  #pragma unroll
  for (int p = 0; p < 3; ++p) {
    int j = p*64 + d;
    bf16x8 bi0 = *(const bf16x8*)(gwihB + j*64 + kq*8);
    bf16x8 bi1 = *(const bf16x8*)(gwihB + j*64 + 32 + kq*8);
    bf16x8 bh0 = *(const bf16x8*)(gwhhB + j*64 + kq*8);
    bf16x8 bh1 = *(const bf16x8*)(gwhhB + j*64 + 32 + kq*8);
    #pragma unroll
    for (int t = 0; t < 2; ++t) {
      f32x4 a = __builtin_amdgcn_mfma_f32_16x16x32_bf16(mrf[t][0], bi0, zero4, 0, 0, 0);
      gi[t][p] = __builtin_amdgcn_mfma_f32_16x16x32_bf16(mrf[t][1], bi1, a, 0, 0, 0);
      f32x4 b = __builtin_amdgcn_mfma_f32_16x16x32_bf16(hf[t][0], bh0, zero4, 0, 0, 0);
      gh[t][p] = __builtin_amdgcn_mfma_f32_16x16x32_bf16(hf[t][1], bh1, b, 0, 0, 0);
    }
  }
  float bir = bih[d],      bhr = bhh[d];
  float biz = bih[64 + d], bhz = bhh[64 + d];
  float bin = bih[128 + d], bhn = bhh[128 + d];
  __syncthreads();   // all h-fragment reads done before any h write
  #pragma unroll
  for (int t = 0; t < 2; ++t) {
    #pragma unroll
    for (int r = 0; r < 4; ++r) {
      int node = nb + t*16 + kq*4 + r;
      float rr = sigm(gi[t][0][r] + bir + gh[t][0][r] + bhr);
      float z  = sigm(gi[t][1][r] + biz + gh[t][1][r] + bhz);
      float nn = tanhf(gi[t][2][r] + bin + rr * (gh[t][2][r] + bhn));
      float hv = h[node*64 + d];
      float hn = (1.f - z) * nn + z * hv;
      h[node*64 + d] = hn;
      out[node*64 + d] = hn + out[node*64 + d];
    }
  }
}

// ---------------- global mean pool (atomic) ----------------
__global__ void k_pool(const float* __restrict__ out, const int* __restrict__ batch,
                       float* __restrict__ pooled, float* __restrict__ pcnt) {
  int idx = blockIdx.x * 256 + threadIdx.x;
  int n = idx >> 6, d = idx & 63;
  int b = batch[n];
  atomicAdd(&pooled[b*64 + d], out[idx]);
  if (d == 0) atomicAdd(&pcnt[b], 1.f);
}

// ---------------- post FC + output ----------------
__global__ void k_final(const float* __restrict__ pooled, const float* __restrict__ pcnt,
                        const float* __restrict__ postW, const float* __restrict__ postb,
                        const float* __restrict__ outW, const float* __restrict__ outb,
                        float* __restrict__ y) {
  int b = blockIdx.x, d = threadIdx.x;
  __shared__ float pl[64];
  float c = fmaxf(pcnt[b], 1.f);
  pl[d] = pooled[b*64 + d] / c;
  __syncthreads();
  float acc = postb[d];
  #pragma unroll 8
  for (int k = 0; k < 64; ++k) acc += pl[k] * postW[k*64 + d];
  acc = fmaxf(acc, 0.f);
  float v = acc * outW[d];
  #pragma unroll
  for (int off = 32; off > 0; off >>= 1) v += __shfl_down(v, off, 64);
  if (d == 0) y[b] = v + outb[0];
}

extern "C" void kernel_launch(void* const* d_in, const int* in_sizes, int n_in,
                              void* d_out, int out_size, void* d_ws, size_t ws_size,
                              hipStream_t stream) {
  (void)in_sizes; (void)n_in; (void)out_size; (void)ws_size;
  const float* x        = (const float*)d_in[0];
  const float* edge_attr= (const float*)d_in[1];
  const float* preW     = (const float*)d_in[2];
  const float* preb     = (const float*)d_in[3];
  const float* ew1      = (const float*)d_in[4];
  const float* eb1      = (const float*)d_in[5];
  const float* ew2      = (const float*)d_in[6];
  const float* eb2      = (const float*)d_in[7];
  const float* rootw    = (const float*)d_in[8];
  const float* rootb    = (const float*)d_in[9];
  const float* gwih     = (const float*)d_in[10];
  const float* gwhh     = (const float*)d_in[11];
  const float* gbih     = (const float*)d_in[12];
  const float* gbhh     = (const float*)d_in[13];
  const float* gnlin    = (const float*)d_in[14];
  const float* gngamma  = (const float*)d_in[15];
  const float* gnbeta   = (const float*)d_in[16];
  const float* postW    = (const float*)d_in[17];
  const float* postb    = (const float*)d_in[18];
  const float* outW     = (const float*)d_in[19];
  const float* outb     = (const float*)d_in[20];
  const int*   eidx     = (const int*)d_in[21];
  const int*   batch    = (const int*)d_in[22];
  const int* src = eidx;
  const int* dst = eidx + Ee;
  float* y = (float*)d_out;

  float* ws     = (float*)d_ws;
  float* out    = ws;                     // N*64
  float* hbuf   = out    + Nn*64;
  float* mbuf   = hbuf   + Nn*64;
  float* sbuf   = mbuf   + Nn*64;         // N*16
  float* agg    = sbuf   + Nn*16;         // N*64
  float* stats  = agg    + Nn*64;         // 2048 (contiguous with agg: 1 memset)
  float* cnt    = stats  + 2048;          // N
  float* pooled = cnt    + Nn;            // N (>= B*64)
  float* pcnt   = pooled + Nn;            // 64
  float* bfbase = pcnt   + 64;
  short* w1T    = (short*)bfbase;         // 3*4096
  short* b2T    = w1T    + 3*4096;
  short* w2T    = b2T    + 3*4096;        // 3*262144
  short* rootwT = w2T    + 3*262144;      // 3*4096
  short* gwihB  = rootwT + 3*4096;        // 3*12288
  short* gwhhB  = gwihB  + 3*12288;       // 3*12288
  short* preWT  = gwhhB  + 3*12288;       // 8192

  hipMemsetAsync(cnt, 0, (Nn + Nn + 64)*sizeof(float), stream);

  k_prep<<<3072, 256, 0, stream>>>(ew1, ew2, eb2, rootw, gwih, gwhh, preW,
                                   w1T, b2T, w2T, rootwT, gwihB, gwhhB, preWT);
  k_tkl<<<1, 256, 0, stream>>>(preW, preb, postW, postb, outW, outb, y);
  k_count<<<Ee/256, 256, 0, stream>>>(dst, cnt);
  k_pre<<<Nn/32, 256, 0, stream>>>(x, preWT, preb, out, hbuf);

  for (int i = 0; i < 3; ++i) {
    hipMemsetAsync(agg, 0, (Nn*64 + 2048)*sizeof(float), stream);
    k_msg<<<Ee/64, 256, 0, stream>>>(out, edge_attr,
                                     w1T + i*4096, eb1 + i*64,
                                     w2T + i*262144, b2T + i*4096,
                                     src, dst, agg);
    k_m_fused<<<Nn/64, 256, 0, stream>>>(agg, cnt, out, rootwT + i*4096,
                                         rootb + i*64, gnlin + i*640, mbuf, sbuf, stats);
    k_gru<<<Nn/32, 256, 0, stream>>>(mbuf, sbuf, stats, gngamma + i*640, gnbeta + i*640,
                                     gwihB + i*12288, gwhhB + i*12288,
                                     gbih + i*192, gbhh + i*192, hbuf, out);
  }

  k_pool<<<Nn*64/256, 256, 0, stream>>>(out, batch, pooled, pcnt);
  k_final<<<Bb, 64, 0, stream>>>(pooled, pcnt, postW, postb, outW, outb, y);
}